// Round 16
// baseline (81.638 us; speedup 1.0000x reference)
//
#include <hip/hip_runtime.h>
#include <hip/hip_bf16.h>
#include <math.h>

#define T_TOK   1024
#define D_DIM   1024
#define E_NUM   8
#define F_DIM   768
#define N_SLOTS 2048

typedef unsigned short u16;
typedef unsigned int   u32;
typedef __attribute__((ext_vector_type(8))) short bf16x8;
typedef __attribute__((ext_vector_type(4))) float f32x4;

// ---- workspace layout (byte offsets) ----
#define WS_SEL    0
#define WS_WTS    8192
#define WS_BUCKET 16384
#define WS_COUNTS 49152
#define WS_OFFS   49216
#define WS_POS    49280
#define WS_XB     65536                      // bf16[1024][1024]    2 MB
#define WS_H      (WS_XB + 2097152)          // bf16[3072][768]     4.7 MB
#define WS_Y      (WS_H + 4718592)           // f32 [3072][1024]    12.6 MB
#define WS_WGUT   (WS_Y + 12582912)          // bf16[8][1536][1024] 25.2 MB
#define WS_WGUST  (WS_WGUT + 25165824)       // bf16[1536][1024]    3.1 MB
// total ~50.7 MB

__device__ __forceinline__ u16 f2bf(float x) {            // RNE
    u32 u = __float_as_uint(x);
    u += 0x7fffu + ((u >> 16) & 1u);
    return (u16)(u >> 16);
}
// pack 2 fp32 -> 2 bf16 (truncate) in one v_perm_b32: result = [hi.bf16 | lo.bf16]
#define PKBF(hi, lo) __builtin_amdgcn_perm(__float_as_uint(hi), __float_as_uint(lo), 0x07060302u)

// async global->LDS, 16B per lane. LDS dest = wave-uniform base + lane*16.
__device__ __forceinline__ void async16(const void* g, void* s) {
    __builtin_amdgcn_global_load_lds(
        (const __attribute__((address_space(1))) unsigned int*)g,
        (__attribute__((address_space(3))) unsigned int*)s, 16, 0, 0);
}

#define PIN()   __builtin_amdgcn_sched_barrier(0)
#define BAR()   do { PIN(); __builtin_amdgcn_s_barrier(); PIN(); } while (0)
#define WAIT6() do { asm volatile("s_waitcnt vmcnt(6)" ::: "memory"); PIN(); } while (0)
#define WAIT0() do { asm volatile("s_waitcnt vmcnt(0)" ::: "memory"); PIN(); } while (0)

// 64x64 transpose+cvt tile helper (fp32 [R][C] src -> bf16 [C-major][R] dst)
__device__ __forceinline__ void tr_tile(
    const float* __restrict__ src, u16* __restrict__ dst,
    int R, int C, int r0, int c0, u16 (*tile)[72])
{
    int t = threadIdx.x;
    int rr = t >> 4, cq = (t & 15) * 4;
#pragma unroll
    for (int i = 0; i < 4; ++i) {
        int rl = rr + 16 * i;
        float4 v = *(const float4*)(src + (size_t)(r0 + rl) * C + c0 + cq);
        tile[cq + 0][rl] = f2bf(v.x);
        tile[cq + 1][rl] = f2bf(v.y);
        tile[cq + 2][rl] = f2bf(v.z);
        tile[cq + 3][rl] = f2bf(v.w);
    }
    __syncthreads();
#pragma unroll
    for (int j = 0; j < 2; ++j) {
        int idx = t + 256 * j;
        int cc = idx >> 3, q = idx & 7;
        *(uint4*)(dst + (size_t)(c0 + cc) * R + r0 + q * 8) = *(const uint4*)&tile[cc][q * 8];
    }
}

// ---------------- prep1: transpose Wg/Wu/Wgs/Wus (blocks 0..3455) + xrouter (3456..3711) ----------------
__global__ __launch_bounds__(256) void prep1_kernel(
    const float* __restrict__ X, const float* __restrict__ Wr,
    const float* __restrict__ bias,
    const float* __restrict__ Wg, const float* __restrict__ Wu,
    const float* __restrict__ Wgs, const float* __restrict__ Wus,
    u16* __restrict__ Xb, int* __restrict__ sel, float* __restrict__ wts,
    u16* __restrict__ Wgut, u16* __restrict__ Wgust)
{
    const int i = blockIdx.x;
    if (i < 3456) {
        __shared__ u16 tile[64][72];
        const int z = i / 192;
        const int rem = i - z * 192;
        const int rtile = rem / 12, ctile = rem - rtile * 12;   // R=1024 (16), C=768 (12)
        const float* src; u16* dst;
        if (z < 8)       { src = Wg + (size_t)z * D_DIM * F_DIM;       dst = Wgut + (size_t)z * 1536 * D_DIM; }
        else if (z < 16) { src = Wu + (size_t)(z - 8) * D_DIM * F_DIM; dst = Wgut + (size_t)(z - 8) * 1536 * D_DIM + (size_t)F_DIM * D_DIM; }
        else if (z == 16){ src = Wgs; dst = Wgust; }
        else             { src = Wus; dst = Wgust + (size_t)F_DIM * D_DIM; }
        tr_tile(src, dst, D_DIM, F_DIM, rtile * 64, ctile * 64, tile);
        return;
    }
    // ---- xrouter: bf16-convert X row + router top-2 (one wave per token) ----
    int t = (i - 3456) * 4 + (threadIdx.x >> 6);
    int lane = threadIdx.x & 63;
    const float* xrow = X + (size_t)t * D_DIM;
    u16* brow = Xb + (size_t)t * D_DIM;
    float acc[E_NUM];
#pragma unroll
    for (int e = 0; e < E_NUM; ++e) acc[e] = 0.f;
#pragma unroll
    for (int q = 0; q < 4; ++q) {
        int d = q * 256 + lane * 4;
        float4 v = *(const float4*)(xrow + d);
        ushort4 o;
        o.x = f2bf(v.x); o.y = f2bf(v.y); o.z = f2bf(v.z); o.w = f2bf(v.w);
        *(ushort4*)(brow + d) = o;
        const float xv[4] = {v.x, v.y, v.z, v.w};
#pragma unroll
        for (int jj = 0; jj < 4; ++jj) {
            const float4* wr = (const float4*)(Wr + (size_t)(d + jj) * E_NUM);
            float4 w0 = wr[0], w1 = wr[1];
            acc[0] += xv[jj] * w0.x; acc[1] += xv[jj] * w0.y;
            acc[2] += xv[jj] * w0.z; acc[3] += xv[jj] * w0.w;
            acc[4] += xv[jj] * w1.x; acc[5] += xv[jj] * w1.y;
            acc[6] += xv[jj] * w1.z; acc[7] += xv[jj] * w1.w;
        }
    }
#pragma unroll
    for (int e = 0; e < E_NUM; ++e)
#pragma unroll
        for (int off = 32; off > 0; off >>= 1)
            acc[e] += __shfl_xor(acc[e], off);
    if (lane == 0) {
        float s[E_NUM], b[E_NUM];
#pragma unroll
        for (int e = 0; e < E_NUM; ++e) {
            s[e] = 1.f / (1.f + expf(-acc[e]));
            b[e] = s[e] + bias[e];
        }
        int i1 = 0; float b1 = b[0];
#pragma unroll
        for (int e = 1; e < E_NUM; ++e) if (b[e] > b1) { b1 = b[e]; i1 = e; }
        int i2 = -1; float b2 = -INFINITY;
#pragma unroll
        for (int e = 0; e < E_NUM; ++e) {
            if (e == i1) continue;
            if (b[e] > b2) { b2 = b[e]; i2 = e; }
        }
        float s1 = s[i1], s2 = s[i2];
        float denom = s1 + s2 + 1e-20f;
        sel[2 * t] = i1; sel[2 * t + 1] = i2;
        wts[2 * t] = s1 / denom; wts[2 * t + 1] = s2 / denom;
    }
}

// ---------------- dispatch ----------------
__global__ __launch_bounds__(512) void dispatch_kernel(
    const int* __restrict__ sel, int* __restrict__ bucket,
    int* __restrict__ counts, int* __restrict__ offs, int* __restrict__ pos)
{
    __shared__ int soffs[E_NUM + 1];
    int e = threadIdx.x >> 6;
    int lane = threadIdx.x & 63;
    int running = 0;
    for (int base = 0; base < N_SLOTS; base += 64) {
        int slot = base + lane;
        bool mine = (sel[slot] == e);
        unsigned long long mask = __ballot(mine);
        if (mine) {
            int rank = running + __popcll(mask & ((1ull << lane) - 1ull));
            bucket[e * T_TOK + rank] = slot;
        }
        running += __popcll(mask);
    }
    if (lane == 0) counts[e] = running;
    __syncthreads();
    if (threadIdx.x == 0) {
        int o = 0;
        for (int k = 0; k < E_NUM; ++k) { soffs[k] = o; offs[k] = o; o += counts[k]; }
        soffs[E_NUM] = o; offs[E_NUM] = o;
    }
    __syncthreads();
    int base_off = soffs[e];
    for (int r = lane; r < running; r += 64)
        pos[bucket[e * T_TOK + r]] = base_off + r;
}

// ================= proj1: H = silu(Xb@Wg^T) * (Xb@Wu^T)  (R7 exact, trimmed grid) =================
// BM=64, gate64+up64, BK=64, async16 staging + counted vmcnt(6).
// grid 1792: cxcd=i&7, m=i>>3, y=m&15, phi=m>>4; panel=phi*8+cxcd (<108); unit=panel/12, x=panel%12
__global__ __launch_bounds__(256, 3) void proj1(
    const u16* __restrict__ Xb, const u16* __restrict__ Wgut, const u16* __restrict__ Wgust,
    u16* __restrict__ H,
    const int* __restrict__ bucket, const int* __restrict__ counts, const int* __restrict__ offs)
{
    const int i = blockIdx.x;
    const int cxcd = i & 7, m = i >> 3;
    const int y = m & 15, phi = m >> 4;
    const int panel = phi * 8 + cxcd;
    if (panel >= 108) return;
    const int unit = panel / 12, x = panel - unit * 12;

    int nrows, rbase; const u16* Wt;
    if (unit < E_NUM) {
        nrows = counts[unit]; rbase = offs[unit];
        Wt = Wgut + (size_t)unit * 1536 * D_DIM;
    } else {
        nrows = T_TOK; rbase = N_SLOTS; Wt = Wgust;
    }
    const int row0 = y * 64;
    if (row0 >= nrows) return;

    // LDS rows: 0..63 A, 64..127 gate B, 128..191 up B; row = 64 u16 (128B, 8 chunks)
    __shared__ u16 smem[2][192 * 64];

    const int t = threadIdx.x;
    const int wv = t >> 6, lane = t & 63, l15 = lane & 15, lg = lane >> 4;
    const int wm = wv >> 1, wn = wv & 1;
    const int rl = lane >> 3, cch = lane & 7;

    const u16* srcA[2];
#pragma unroll
    for (int j = 0; j < 2; ++j) {
        int arow = wv * 16 + j * 8 + rl;                 // 0..63
        int grow = min(row0 + arow, nrows - 1);
        if (unit < E_NUM) grow = bucket[unit * T_TOK + grow] >> 1;
        srcA[j] = Xb + (size_t)grow * D_DIM + (cch ^ (arow & 7)) * 8;
    }
    const u16* srcB[4];
#pragma unroll
    for (int j = 0; j < 4; ++j) {
        int br = wv * 32 + j * 8 + rl;                   // 0..127 (0..63 gate, 64..127 up)
        size_t n = (size_t)(br >> 6) * F_DIM + x * 64 + (br & 63);
        srcB[j] = Wt + n * D_DIM + (cch ^ (br & 7)) * 8;
    }

    f32x4 accg[2][2], accu[2][2];
    const f32x4 z4 = {0.f, 0.f, 0.f, 0.f};
#pragma unroll
    for (int ri = 0; ri < 2; ++ri)
#pragma unroll
        for (int ci = 0; ci < 2; ++ci) { accg[ri][ci] = z4; accu[ri][ci] = z4; }

#define STAGE1(buf, kt) do { \
    _Pragma("unroll") \
    for (int j = 0; j < 2; ++j) \
        async16(srcA[j] + (kt), &smem[buf][(wv * 16 + j * 8) * 64]); \
    _Pragma("unroll") \
    for (int j = 0; j < 4; ++j) \
        async16(srcB[j] + (kt), &smem[buf][(64 + wv * 32 + j * 8) * 64]); \
} while (0)

#define COMP1(buf) do { \
    bf16x8 av[2][2], bg[2][2], bu[2][2]; \
    _Pragma("unroll") \
    for (int ri = 0; ri < 2; ++ri) { \
        int row = wm * 32 + ri * 16 + l15; \
        _Pragma("unroll") \
        for (int kk = 0; kk < 2; ++kk) { \
            int ch = ((kk << 2) | lg) ^ (row & 7); \
            av[ri][kk] = *(const bf16x8*)&smem[buf][row * 64 + ch * 8]; \
        } \
    } \
    _Pragma("unroll") \
    for (int ci = 0; ci < 2; ++ci) { \
        int br = wn * 32 + ci * 16 + l15; \
        _Pragma("unroll") \
        for (int kk = 0; kk < 2; ++kk) { \
            int ch = ((kk << 2) | lg) ^ (br & 7); \
            bg[ci][kk] = *(const bf16x8*)&smem[buf][(64 + br) * 64 + ch * 8]; \
            bu[ci][kk] = *(const bf16x8*)&smem[buf][(128 + br) * 64 + ch * 8]; \
        } \
    } \
    _Pragma("unroll") \
    for (int kk = 0; kk < 2; ++kk) \
        _Pragma("unroll") \
        for (int ri = 0; ri < 2; ++ri) \
            _Pragma("unroll") \
            for (int ci = 0; ci < 2; ++ci) { \
                accg[ri][ci] = __builtin_amdgcn_mfma_f32_16x16x32_bf16( \
                    av[ri][kk], bg[ci][kk], accg[ri][ci], 0, 0, 0); \
                accu[ri][ci] = __builtin_amdgcn_mfma_f32_16x16x32_bf16( \
                    av[ri][kk], bu[ci][kk], accu[ri][ci], 0, 0, 0); \
            } \
} while (0)

    STAGE1(0, 0);
    for (int tt = 0; tt < 16; tt += 2) {
        STAGE1(1, (tt + 1) * 64);
        WAIT6();
        BAR();
        COMP1(0);
        BAR();
        if (tt + 2 < 16) { STAGE1(0, (tt + 2) * 64); WAIT6(); }
        else             { WAIT0(); }
        BAR();
        COMP1(1);
        BAR();
    }
#undef STAGE1
#undef COMP1

    // epilogue: fused SiLU-GLU, write H bf16
#pragma unroll
    for (int ri = 0; ri < 2; ++ri)
#pragma unroll
        for (int ci = 0; ci < 2; ++ci) {
            int n = x * 64 + wn * 32 + ci * 16 + l15;
#pragma unroll
            for (int r = 0; r < 4; ++r) {
                int row = row0 + wm * 32 + ri * 16 + lg * 4 + r;
                if (row >= nrows) continue;
                float gv = accg[ri][ci][r];
                float uv = accu[ri][ci][r];
                H[(size_t)(rbase + row) * F_DIM + n] =
                    f2bf(gv / (1.f + __expf(-gv)) * uv);
            }
        }
}

// ================= proj2: Y = H @ Wd, fp32 weights read directly (R15 exact) =================
// BM=64, BN=64, BK=64, 12 K-steps, 1-deep dbuf. LDS rows 0..63 A, 64..127 B.
// grid 2304: cxcd=i&7, m=i>>3, y=m&15, phi=m>>4; panel=phi*8+cxcd (<144); unit=panel>>4, x=panel&15
__global__ __launch_bounds__(256, 3) void proj2(
    const u16* __restrict__ H,
    const float* __restrict__ Wd, const float* __restrict__ Wds,
    float* __restrict__ Y,
    const int* __restrict__ counts, const int* __restrict__ offs)
{
    const int i = blockIdx.x;
    const int cxcd = i & 7, m = i >> 3;
    const int y = m & 15, phi = m >> 4;
    const int panel = phi * 8 + cxcd;
    if (panel >= 144) return;
    const int unit = panel >> 4, x = panel & 15;

    int nrows, rbase; const float* Bm;
    if (unit < E_NUM) {
        nrows = counts[unit]; rbase = offs[unit];
        Bm = Wd + (size_t)unit * F_DIM * D_DIM;
    } else { nrows = T_TOK; rbase = N_SLOTS; Bm = Wds; }
    const int row0 = y * 64;
    if (row0 >= nrows) return;

    __shared__ u16 smem[2][128 * 64];

    const int t = threadIdx.x;
    const int wv = t >> 6, lane = t & 63, l15 = lane & 15, g = lane >> 4;
    const int wm = wv >> 1, wn = wv & 1;

    const int ar = t >> 2, ac = t & 3;
    const int grow = rbase + min(row0 + ar, nrows - 1);
    const u16* srcA = H + (size_t)grow * F_DIM + ac * 8;
    const int wA0 = ar * 64 + ((ac     ^ (ar & 7)) * 8);
    const int wA1 = ar * 64 + (((ac+4) ^ (ar & 7)) * 8);

    const int bn = t & 63;
    const int bq = t >> 6;
    const float* srcB = Bm + (size_t)(bq * 16) * D_DIM + x * 64 + bn;
    int wB[2];
#pragma unroll
    for (int q = 0; q < 2; ++q)
        wB[q] = (64 + bn) * 64 + (((bq * 2 + q) ^ (bn & 7)) * 8);

    f32x4 acc[2][2];
    const f32x4 z4 = {0.f, 0.f, 0.f, 0.f};
#pragma unroll
    for (int ri = 0; ri < 2; ++ri)
#pragma unroll
        for (int ci = 0; ci < 2; ++ci) acc[ri][ci] = z4;

    uint4 pa0, pa1;
    float pb[16];
#define LOAD2(kt) do { \
    pa0 = *(const uint4*)(srcA + (kt)); \
    pa1 = *(const uint4*)(srcA + (kt) + 32); \
    const float* _bp = srcB + (size_t)(kt) * D_DIM; \
    _Pragma("unroll") \
    for (int ii = 0; ii < 16; ++ii) pb[ii] = _bp[(size_t)ii * D_DIM]; \
} while (0)
#define WRITE2(buf) do { \
    *(uint4*)&smem[buf][wA0] = pa0; \
    *(uint4*)&smem[buf][wA1] = pa1; \
    _Pragma("unroll") \
    for (int q = 0; q < 2; ++q) { \
        u32 pk[4]; \
        _Pragma("unroll") \
        for (int j = 0; j < 4; ++j) pk[j] = PKBF(pb[8*q + 2*j + 1], pb[8*q + 2*j]); \
        *(uint4*)&smem[buf][wB[q]] = *(const uint4*)pk; \
    } \
} while (0)
#define COMP2(buf) do { \
    const u16* _p = smem[buf]; \
    _Pragma("unroll") \
    for (int kk = 0; kk < 2; ++kk) { \
        const int ch = (((kk << 2) | g) ^ (l15 & 7)) * 8; \
        bf16x8 _a[2], _b[2]; \
        _Pragma("unroll") \
        for (int ri = 0; ri < 2; ++ri) \
            _a[ri] = *(const bf16x8*)&_p[(wm * 32 + ri * 16 + l15) * 64 + ch]; \
        _Pragma("unroll") \
        for (int ci = 0; ci < 2; ++ci) \
            _b[ci] = *(const bf16x8*)&_p[(64 + wn * 32 + ci * 16 + l15) * 64 + ch]; \
        _Pragma("unroll") \
        for (int ri = 0; ri < 2; ++ri) \
            _Pragma("unroll") \
            for (int ci = 0; ci < 2; ++ci) \
                acc[ri][ci] = __builtin_amdgcn_mfma_f32_16x16x32_bf16(_a[ri], _b[ci], acc[ri][ci], 0, 0, 0); \
    } \
} while (0)

    LOAD2(0);
    for (int tt = 0; tt < 12; ++tt) {
        WRITE2(tt & 1);
        if (tt + 1 < 12) LOAD2((tt + 1) * 64);
        __syncthreads();
        COMP2(tt & 1);
    }
#undef LOAD2
#undef WRITE2
#undef COMP2

#pragma unroll
    for (int ri = 0; ri < 2; ++ri)
#pragma unroll
        for (int ci = 0; ci < 2; ++ci) {
            int n = x * 64 + wn * 32 + ci * 16 + l15;
#pragma unroll
            for (int r = 0; r < 4; ++r) {
                int row = row0 + wm * 32 + ri * 16 + g * 4 + r;
                if (row >= nrows) continue;
                Y[(size_t)(rbase + row) * D_DIM + n] = acc[ri][ci][r];
            }
        }
}

// ---------------- combine ----------------
__global__ __launch_bounds__(256) void combine_kernel(
    const float* __restrict__ Y, const int* __restrict__ pos,
    const float* __restrict__ wts, float* __restrict__ out)
{
    int t = blockIdx.x;
    int d = threadIdx.x * 4;
    int p0 = pos[2 * t], p1 = pos[2 * t + 1];
    float w0 = wts[2 * t], w1 = wts[2 * t + 1];
    float4 a = *(const float4*)(Y + (size_t)(N_SLOTS + t) * D_DIM + d);
    float4 b = *(const float4*)(Y + (size_t)p0 * D_DIM + d);
    float4 cc = *(const float4*)(Y + (size_t)p1 * D_DIM + d);
    float4 o;
    o.x = a.x + w0 * b.x + w1 * cc.x;
    o.y = a.y + w0 * b.y + w1 * cc.y;
    o.z = a.z + w0 * b.z + w1 * cc.z;
    o.w = a.w + w0 * b.w + w1 * cc.w;
    *(float4*)(out + (size_t)t * D_DIM + d) = o;
}

extern "C" void kernel_launch(void* const* d_in, const int* in_sizes, int n_in,
                              void* d_out, int out_size, void* d_ws, size_t ws_size,
                              hipStream_t stream) {
    const float* X    = (const float*)d_in[0];
    const float* Wr   = (const float*)d_in[1];
    const float* bias = (const float*)d_in[2];
    const float* Wg   = (const float*)d_in[3];
    const float* Wu   = (const float*)d_in[4];
    const float* Wd   = (const float*)d_in[5];
    const float* Wgs  = (const float*)d_in[6];
    const float* Wus  = (const float*)d_in[7];
    const float* Wds  = (const float*)d_in[8];
    float* out = (float*)d_out;

    char* ws = (char*)d_ws;
    int*   sel    = (int*)(ws + WS_SEL);
    float* wtsv   = (float*)(ws + WS_WTS);
    int*   bucket = (int*)(ws + WS_BUCKET);
    int*   counts = (int*)(ws + WS_COUNTS);
    int*   offs   = (int*)(ws + WS_OFFS);
    int*   pos    = (int*)(ws + WS_POS);
    u16*   Xb     = (u16*)(ws + WS_XB);
    u16*   H      = (u16*)(ws + WS_H);
    float* Y      = (float*)(ws + WS_Y);
    u16*   Wgut   = (u16*)(ws + WS_WGUT);
    u16*   Wgust  = (u16*)(ws + WS_WGUST);

    prep1_kernel<<<3712, 256, 0, stream>>>(
        X, Wr, bias, Wg, Wu, Wgs, Wus, Xb, sel, wtsv, Wgut, Wgust);
    dispatch_kernel<<<1, 512, 0, stream>>>(sel, bucket, counts, offs, pos);

    proj1<<<1792, 256, 0, stream>>>(Xb, Wgut, Wgust, H, bucket, counts, offs);
    proj2<<<2304, 256, 0, stream>>>(H, Wd, Wds, Y, counts, offs);
    combine_kernel<<<T_TOK, 256, 0, stream>>>(Y, pos, wtsv, out);
}